// Round 6
// baseline (133.598 us; speedup 1.0000x reference)
//
#include <hip/hip_runtime.h>
#include <cstdint>
#include <cstddef>

// Problem constants (fixed by the reference: N=4096, D=512)
constexpr int N_ROWS = 4096;
constexpr int D      = 512;
constexpr int M      = 8192;   // 2N
constexpr int NTILE  = 64;     // M / 128 : partials chunk grid
constexpr int NT2    = 32;     // M / 256 : 256^2 tile grid
constexpr int NJOB2  = NT2 * (NT2 + 1) / 2;   // 528 upper-tri tile pairs
constexpr int BKB    = 64;     // K-bytes per iter (fp8, K=64)
constexpr int NKT    = D / BKB;                // 8 K-iterations
constexpr int TBY    = 256 * BKB;              // 16 KB per LDS K-buffer (256 rows)

using f32x16 = __attribute__((ext_vector_type(16))) float;
using i32x4  = __attribute__((ext_vector_type(4))) int;
using i32x8  = __attribute__((ext_vector_type(8))) int;
using ul2    = __attribute__((ext_vector_type(2))) unsigned long;

// 16B async global->LDS copy. LDS dest is wave-uniform base + lane*16.
#define ASYNC_CP16(gsrc, ldst)                                                      \
    __builtin_amdgcn_global_load_lds(                                               \
        (const __attribute__((address_space(1))) unsigned int*)(gsrc),              \
        (__attribute__((address_space(3))) unsigned int*)(ldst), 16, 0, 0)

// sum of squares of the 4 fp8 e4m3 bytes in `pk` (selector must be literal)
#define SS_FP8(pk, accum)                                                           \
    do {                                                                            \
        float f0 = __builtin_amdgcn_cvt_f32_fp8((pk), 0);                           \
        float f1 = __builtin_amdgcn_cvt_f32_fp8((pk), 1);                           \
        float f2 = __builtin_amdgcn_cvt_f32_fp8((pk), 2);                           \
        float f3 = __builtin_amdgcn_cvt_f32_fp8((pk), 3);                           \
        (accum) += f0 * f0 + f1 * f1 + f2 * f2 + f3 * f3;                           \
    } while (0)

// ---------------------------------------------------------------------------
// Kernel 1: fused normalize + fp8-quantize + positive-pair logits (VERIFIED).
// Z rows stored fp8 e4m3 PRE-SWIZZLED: within each 64B block, 16B chunk c at
// physical chunk c ^ ((row>>1)&3) -> GEMM staging source is lane-monotonic
// and the LDS image matches the ds_read swizzle. diagss from QUANTIZED
// values; pos fp32-exact.
// ---------------------------------------------------------------------------
__global__ __launch_bounds__(256) void normpos_kernel(
    const float* __restrict__ emb_i, const float* __restrict__ emb_j,
    uint8_t* __restrict__ zb, float* __restrict__ diagss,
    float* __restrict__ pos)
{
    const int wave = threadIdx.x >> 6, lane = threadIdx.x & 63;
    const int k = blockIdx.x * 4 + wave;

    const float4* a = (const float4*)(emb_i + (size_t)k * D);
    const float4* b = (const float4*)(emb_j + (size_t)k * D);
    float4 a0 = a[lane * 2], a1 = a[lane * 2 + 1];
    float4 b0 = b[lane * 2], b1 = b[lane * 2 + 1];

    float ssi = a0.x*a0.x + a0.y*a0.y + a0.z*a0.z + a0.w*a0.w
              + a1.x*a1.x + a1.y*a1.y + a1.z*a1.z + a1.w*a1.w;
    float ssj = b0.x*b0.x + b0.y*b0.y + b0.z*b0.z + b0.w*b0.w
              + b1.x*b1.x + b1.y*b1.y + b1.z*b1.z + b1.w*b1.w;
    float dp  = a0.x*b0.x + a0.y*b0.y + a0.z*b0.z + a0.w*b0.w
              + a1.x*b1.x + a1.y*b1.y + a1.z*b1.z + a1.w*b1.w;
    #pragma unroll
    for (int off = 32; off; off >>= 1) {
        ssi += __shfl_xor(ssi, off, 64);
        ssj += __shfl_xor(ssj, off, 64);
        dp  += __shfl_xor(dp,  off, 64);
    }
    const float invi = rsqrtf(ssi), invj = rsqrtf(ssj);

    const float zi[8] = {a0.x*invi, a0.y*invi, a0.z*invi, a0.w*invi,
                         a1.x*invi, a1.y*invi, a1.z*invi, a1.w*invi};
    const float zj[8] = {b0.x*invj, b0.y*invj, b0.z*invj, b0.w*invj,
                         b1.x*invj, b1.y*invj, b1.z*invj, b1.w*invj};

    int pi0 = __builtin_amdgcn_cvt_pk_fp8_f32(zi[0], zi[1], 0, false);
    pi0     = __builtin_amdgcn_cvt_pk_fp8_f32(zi[2], zi[3], pi0, true);
    int pi1 = __builtin_amdgcn_cvt_pk_fp8_f32(zi[4], zi[5], 0, false);
    pi1     = __builtin_amdgcn_cvt_pk_fp8_f32(zi[6], zi[7], pi1, true);
    int pj0 = __builtin_amdgcn_cvt_pk_fp8_f32(zj[0], zj[1], 0, false);
    pj0     = __builtin_amdgcn_cvt_pk_fp8_f32(zj[2], zj[3], pj0, true);
    int pj1 = __builtin_amdgcn_cvt_pk_fp8_f32(zj[4], zj[5], 0, false);
    pj1     = __builtin_amdgcn_cvt_pk_fp8_f32(zj[6], zj[7], pj1, true);

    float dssi = 0.f, dssj = 0.f;
    SS_FP8(pi0, dssi);
    SS_FP8(pi1, dssi);
    SS_FP8(pj0, dssj);
    SS_FP8(pj1, dssj);

    // Pre-swizzled store. Lane l holds k-bytes [8l, 8l+8): 64B block b=l>>3,
    // logical chunk c=(l>>1)&3, half o=l&1 -> phys b*64 + (c^x)*16 + o*8.
    const int x   = (k >> 1) & 3;
    const int sl8 = (lane >> 3) * 8 + ((((lane >> 1) & 3) ^ x) * 2) + (lane & 1);
    const unsigned long long vi =
        ((unsigned long long)(unsigned)pi1 << 32) | (unsigned)pi0;
    const unsigned long long vj =
        ((unsigned long long)(unsigned)pj1 << 32) | (unsigned)pj0;
    *(unsigned long long*)(zb + (size_t)k * D + sl8 * 8)            = vi;
    *(unsigned long long*)(zb + (size_t)(k + N_ROWS) * D + sl8 * 8) = vj;

    #pragma unroll
    for (int off = 32; off; off >>= 1) {
        dssi += __shfl_xor(dssi, off, 64);
        dssj += __shfl_xor(dssj, off, 64);
    }
    if (lane == 0) {
        diagss[k]          = dssi;
        diagss[k + N_ROWS] = dssj;
        pos[k]             = 2.0f * dp * invi * invj;
    }
}

// ---------------------------------------------------------------------------
// Kernel 2: symmetric fused sim-GEMM, MX fp8 (e4m3, unit scales), 256x256
// tiles -- 2x arithmetic intensity vs the 128^2 plateau.
//
// R5 ledger: 128^2 fp8=39us / MX=46us, 256x128=44us -- all at the SAME
// staging throughput (~5.7 TB/s device, 9.4 B/cy/CU) with every pipe idle.
// Staging bytes, not schedule, is the binding constraint. 256^2 halves
// staged bytes per FLOP: 528 jobs x 8 iters x 32 KB = 135 MB (was 266).
//
// 8 waves (512 thr), wave (wr=w>>2, wc=w&3) owns 128x64 out: acc[4][2] of
// 32x32x64 MX frags (128 acc VGPR). K-loop schedule = R3 verbatim: prime;
// per iter {barrier A; stage(it+1) 4x global_load_lds; vmcnt(4) [own
// stage(it)]; barrier B; 12x ds_read_b128 (XOR swizzle); 8x MFMA}.
// LDS 2x(16+16) KB dbuf + rp/cp = 70 KB.
//
// Partials coverage (each (rc,cc) 128-chunk pair written EXACTLY once):
// tile covers rc in {2bi,2bi+1} x cc in {2bj,2bj+1}. Rows write the full
// 256-col row-sum at cc=2bj and 0 at cc=2bj+1. Mirror cols (bi<bj) write
// the full 256-row col-sum at [2bj+h][2bi] and 0 at [2bj+h][2bi+1].
// Union over tiles: bi'=rc>>1 vs bj'=cc>>1: bi'<bj' rows of (bi',bj');
// bi'==bj' rows of diag tile; bi'>bj' cols of (bj',bi'). Complete.
// ---------------------------------------------------------------------------
__global__ __launch_bounds__(512, 2) void simgemm_kernel(
    const uint8_t* __restrict__ zb, float* __restrict__ partials)
{
    __shared__ ul2 AsV[2 * TBY / 16];   // 32 KB (2 bufs x 16 KB)
    __shared__ ul2 BsV[2 * TBY / 16];   // 32 KB
    __shared__ float rp[8][128];        // per-wave row partials (4 KB)
    __shared__ float cp[8][64];         // per-wave col partials (2 KB)
    uint8_t* As = (uint8_t*)AsV;
    uint8_t* Bs = (uint8_t*)BsV;

    const int tid  = threadIdx.x;
    const int wave = tid >> 6, lane = tid & 63;
    const int l31  = lane & 31, half = lane >> 5;

    // Decode block id -> (bi, bj), bi <= bj over 32x32. cum(bi)=bi*(65-bi)/2.
    const int t = blockIdx.x;
    int bi = (int)((65.0f - sqrtf(4225.0f - 8.0f * (float)t)) * 0.5f);
    if (bi < 0) bi = 0;
    if (bi > 31) bi = 31;
    while (bi > 0 && bi * (65 - bi) / 2 > t) --bi;
    while ((bi + 1) * (65 - (bi + 1)) / 2 <= t) ++bi;
    const int bj = bi + (t - bi * (65 - bi) / 2);
    const bool diag = (bi == bj);

    const int wr = wave >> 2, wc = wave & 3;      // wave tile: rows wr*128, cols wc*64
    const int wrow = wr * 128, wcol = wc * 64;

    // Staging: wave w owns rows [w*32, (w+1)*32) of BOTH A and B.
    // lane l -> row l>>2, 16B chunk l&3 (LINEAR; zb pre-swizzled).
    const int srow = wave * 32 + (lane >> 2);
    const int scol = (lane & 3) * 16;
    const uint8_t* gA = zb + (size_t)(bi * 256 + srow) * D + scol;
    const uint8_t* gB = zb + (size_t)(bj * 256 + srow) * D + scol;
    uint8_t* lA = As + wave * 32 * BKB;
    uint8_t* lB = Bs + wave * 32 * BKB;

#define STAGE4(IT)                                                                  \
    do {                                                                            \
        const int _kc  = (IT) * BKB;                                                \
        const int _off = ((IT) & 1) * TBY;                                          \
        ASYNC_CP16(gA + _kc,          lA + _off);                                   \
        ASYNC_CP16(gA + _kc + 16 * D, lA + _off + 16 * BKB);                        \
        ASYNC_CP16(gB + _kc,          lB + _off);                                   \
        ASYNC_CP16(gB + _kc + 16 * D, lB + _off + 16 * BKB);                        \
    } while (0)

    STAGE4(0);   // prime buffer 0

    f32x16 acc[4][2] = {};
    // lane's 32 contiguous k-bytes: logical chunks 2*half, 2*half+1;
    // physical via row-pair XOR swizzle (wrow/wcol are multiples of 32, so
    // (row>>1)&3 == (l31>>1)&3 -- identical to the verified 128^2 kernel).
    const int c0b = ((2 * half) ^ ((l31 >> 1) & 3)) * 16;

    #pragma unroll
    for (int it = 0; it < NKT; ++it) {
        // (A) all waves finished reading buf (it-1)&1 -> safe to overwrite
        __builtin_amdgcn_s_barrier();
        asm volatile("" ::: "memory");

        if (it + 1 < NKT) {
            STAGE4(it + 1);
            asm volatile("s_waitcnt vmcnt(4)" ::: "memory");   // own stage(it)
        } else {
            asm volatile("s_waitcnt vmcnt(0)" ::: "memory");
        }
        // (B) buf it&1 fully staged by ALL waves
        __builtin_amdgcn_s_barrier();
        asm volatile("" ::: "memory");

        const int cb = (it & 1) * TBY;
        i32x8 af[4], bf[2];
        #pragma unroll
        for (int f = 0; f < 4; ++f) {
            const uint8_t* pa = As + cb + (size_t)(wrow + f * 32 + l31) * BKB;
            i32x4 alo = *(const i32x4*)(pa + c0b);
            i32x4 ahi = *(const i32x4*)(pa + (c0b ^ 16));
            af[f] = __builtin_shufflevector(alo, ahi, 0, 1, 2, 3, 4, 5, 6, 7);
        }
        #pragma unroll
        for (int f = 0; f < 2; ++f) {
            const uint8_t* pb = Bs + cb + (size_t)(wcol + f * 32 + l31) * BKB;
            i32x4 blo = *(const i32x4*)(pb + c0b);
            i32x4 bhi = *(const i32x4*)(pb + (c0b ^ 16));
            bf[f] = __builtin_shufflevector(blo, bhi, 0, 1, 2, 3, 4, 5, 6, 7);
        }
        #pragma unroll
        for (int i = 0; i < 4; ++i)
            #pragma unroll
            for (int j = 0; j < 2; ++j)
                acc[i][j] = __builtin_amdgcn_mfma_scale_f32_32x32x64_f8f6f4(
                    af[i], bf[j], acc[i][j], 0, 0,
                    0, 0x7f7f7f7f, 0, 0x7f7f7f7f);
    }

    // Epilogue. C/D 32x32: col=l31, row=(reg&3)+8*(reg>>2)+4*half.
    // e = exp(sim/T) = exp(2*acc).
    float rowp[4][16] = {};
    #pragma unroll
    for (int j = 0; j < 2; ++j) {
        float cpj = 0.f;
        #pragma unroll
        for (int i = 0; i < 4; ++i)
            #pragma unroll
            for (int r = 0; r < 16; ++r) {
                float e = __expf(2.0f * acc[i][j][r]);
                rowp[i][r] += e;
                cpj += e;
            }
        if (!diag) {   // col partial over this wave's 128 rows
            cpj += __shfl_xor(cpj, 32, 64);
            if (half == 0) cp[wave][j * 32 + l31] = cpj;
        }
    }
    #pragma unroll
    for (int i = 0; i < 4; ++i)
        #pragma unroll
        for (int r = 0; r < 16; ++r) {
            float e = rowp[i][r];
            e += __shfl_xor(e, 1, 64);
            e += __shfl_xor(e, 2, 64);
            e += __shfl_xor(e, 4, 64);
            e += __shfl_xor(e, 8, 64);
            e += __shfl_xor(e, 16, 64);
            if (l31 == 0)
                rp[wave][i * 32 + (r & 3) + 8 * (r >> 2) + 4 * half] = e;
        }
    __syncthreads();

    // Rows: r = tid (0..255). Combine 4 waves (wc=0..3) sharing row-half
    // r>>7. Write full 256-col sum at cc=2bj, zero at cc=2bj+1.
    if (tid < 256) {
        const int rh = tid >> 7, rl = tid & 127;
        const int wb = rh * 4;
        const float v = rp[wb][rl] + rp[wb + 1][rl] + rp[wb + 2][rl] + rp[wb + 3][rl];
        const size_t rc = (size_t)(2 * bi + rh);
        partials[(rc * NTILE + 2 * bj)     * 128 + rl] = v;
        partials[(rc * NTILE + 2 * bj + 1) * 128 + rl] = 0.f;
    } else if (!diag) {
        // Cols (mirror): c = tid-256 (0..255) = wcq*64 + cl. Combine waves
        // wr=0,1 with same wc. Write at [2bj + (c>>7)][2bi], zero sibling.
        const int c = tid - 256;
        const int wcq = c >> 6, cl = c & 63;
        const float v = cp[wcq][cl] + cp[wcq + 4][cl];
        const size_t rc = (size_t)(2 * bj + (c >> 7));
        partials[(rc * NTILE + 2 * bi)     * 128 + (c & 127)] = v;
        partials[(rc * NTILE + 2 * bi + 1) * 128 + (c & 127)] = 0.f;
    }
}

// ---------------------------------------------------------------------------
// Kernel 3: per-tile-row reduction of partials + log terms + pos chunk.
// ---------------------------------------------------------------------------
__global__ __launch_bounds__(256) void rowfin_kernel(
    const float* __restrict__ partials, const float* __restrict__ diagss,
    const float* __restrict__ pos, float* __restrict__ lgpart)
{
    const int r  = blockIdx.x;          // tile-row 0..63
    const int ri = threadIdx.x & 127;   // row within tile
    const int ch = threadIdx.x >> 7;    // c-half 0/1
    const float* base = partials + (size_t)r * NTILE * 128 + ri;
    float s = 0.f;
    #pragma unroll
    for (int c = 0; c < 32; ++c)
        s += base[(size_t)(ch * 32 + c) * 128];
    __shared__ float half1[128];
    __shared__ float red[4];
    if (ch == 1) half1[ri] = s;
    __syncthreads();
    float lg = 0.f;
    if (ch == 0) {
        float rs = s + half1[ri];
        int row = r * 128 + ri;
        lg = __logf(rs - __expf(2.0f * diagss[row]));
    }
    if (threadIdx.x < 64)
        lg -= 2.0f * pos[r * 64 + threadIdx.x];
    #pragma unroll
    for (int off = 32; off; off >>= 1) lg += __shfl_xor(lg, off, 64);
    const int wave = threadIdx.x >> 6, lane = threadIdx.x & 63;
    if (lane == 0) red[wave] = lg;
    __syncthreads();
    if (threadIdx.x == 0) lgpart[r] = red[0] + red[1] + red[2] + red[3];
}

// ---------------------------------------------------------------------------
// Kernel 4: loss = sum_r lgpart[r] / 8192   (one wave)
// ---------------------------------------------------------------------------
__global__ __launch_bounds__(64) void loss_kernel(
    const float* __restrict__ lgpart, float* __restrict__ out)
{
    float local = lgpart[threadIdx.x];
    #pragma unroll
    for (int off = 32; off; off >>= 1) local += __shfl_xor(local, off, 64);
    if (threadIdx.x == 0) out[0] = local * (1.0f / 8192.0f);
}

// ---------------------------------------------------------------------------
extern "C" void kernel_launch(void* const* d_in, const int* in_sizes, int n_in,
                              void* d_out, int out_size, void* d_ws, size_t ws_size,
                              hipStream_t stream)
{
    const float* emb_i = (const float*)d_in[0];
    const float* emb_j = (const float*)d_in[1];

    // ws layout: zb fp8 [M][D] (4 MB) | partials f32[64][64][128] (2 MB)
    //            | diagss f32[M] | pos f32[N] | lgpart f32[64]  (~6.05 MB)
    uint8_t* zb = (uint8_t*)d_ws;
    float* partials = (float*)((char*)d_ws + (size_t)M * D);
    float* diagss   = partials + (size_t)NTILE * NTILE * 128;
    float* pos      = diagss + M;
    float* lgpart   = pos + N_ROWS;
    float* out      = (float*)d_out;

    normpos_kernel<<<N_ROWS / 4, 256, 0, stream>>>(emb_i, emb_j, zb, diagss, pos);
    simgemm_kernel<<<NJOB2, 512, 0, stream>>>(zb, partials);
    rowfin_kernel<<<NTILE, 256, 0, stream>>>(partials, diagss, pos, lgpart);
    loss_kernel<<<1, 64, 0, stream>>>(lgpart, out);
}

// Round 7
// 108.483 us; speedup vs baseline: 1.2315x; 1.2315x over previous
//
#include <hip/hip_runtime.h>
#include <cstdint>
#include <cstddef>

// Problem constants (fixed by the reference: N=4096, D=512)
constexpr int N_ROWS = 4096;
constexpr int D      = 512;
constexpr int M      = 8192;   // 2N
constexpr int NTILE  = 64;     // M / 128 : partials chunk grid
constexpr int NBLK   = NTILE * (NTILE + 1) / 2;   // 2080 upper-tri tile pairs
constexpr int NKT    = 8;      // K-iterations (64 k-bytes each)

using f32x16 = __attribute__((ext_vector_type(16))) float;
using i32x4  = __attribute__((ext_vector_type(4))) int;
using i32x8  = __attribute__((ext_vector_type(8))) int;

// sum of squares of the 4 fp8 e4m3 bytes in `pk` (selector must be literal)
#define SS_FP8(pk, accum)                                                           \
    do {                                                                            \
        float f0 = __builtin_amdgcn_cvt_f32_fp8((pk), 0);                           \
        float f1 = __builtin_amdgcn_cvt_f32_fp8((pk), 1);                           \
        float f2 = __builtin_amdgcn_cvt_f32_fp8((pk), 2);                           \
        float f3 = __builtin_amdgcn_cvt_f32_fp8((pk), 3);                           \
        (accum) += f0 * f0 + f1 * f1 + f2 * f2 + f3 * f3;                           \
    } while (0)

// ---------------------------------------------------------------------------
// zb BLOCKED-TILE layout (fp8 e4m3), designed for direct global->VGPR
// fragment loads with PERFECT coalescing:
//   tile(R, C) = rows [R*32, R*32+32) x k-bytes [C*64, C*64+64), 2048 B,
//   at offset (R*8 + C)*2048.
//   In-tile position of (r, kb2) [kb2 = k-byte within the 64]:
//     g = kb2>>4 (16B group 0..3), b = kb2&15
//     off = (g&1)*1024 + (r*2 + (g>>1))*16 + b
//   MFMA lane (l31 = lane&31, half = lane>>5) needs r=l31, k in
//   [32*half, 32*half+32) = groups {2*half, 2*half+1}:
//     load1 (g=2h, plane 0):  off = (2*l31 + half)*16          -> dense 1 KB
//     load2 (g=2h+1, plane1): off = 1024 + (2*l31 + half)*16   -> dense 1 KB
//   Register image = 32 contiguous k-bytes per lane == the R2-verified MX
//   fragment, so MFMA + C/D handling are unchanged.
// ---------------------------------------------------------------------------

// ---------------------------------------------------------------------------
// Kernel 1: fused normalize + fp8-quantize + positive-pair logits.
// One wave handles PAIR k: row k (emb_i) and row k+N (emb_j).
// Writes zb in the blocked-tile layout above. Lane l holds k-bytes
// [8l, 8l+8) (one 8B half of a 16B group):
//   R=k>>5, r=k&31, C=l>>3, g=(l>>1)&3, b=8*(l&1)
//   off = (R*8 + C)*2048 + ((l>>1)&1)*1024 + (r*2 + ((l>>2)&1))*16 + (l&1)*8
// Row k+4096: R += 128 -> off += 4096/32*8*2048 = N_ROWS*D. Same otherwise.
// diagss from QUANTIZED values; pos fp32-exact.
// ---------------------------------------------------------------------------
__global__ __launch_bounds__(256) void normpos_kernel(
    const float* __restrict__ emb_i, const float* __restrict__ emb_j,
    uint8_t* __restrict__ zb, float* __restrict__ diagss,
    float* __restrict__ pos)
{
    const int wave = threadIdx.x >> 6, lane = threadIdx.x & 63;
    const int k = blockIdx.x * 4 + wave;

    const float4* a = (const float4*)(emb_i + (size_t)k * D);
    const float4* b = (const float4*)(emb_j + (size_t)k * D);
    float4 a0 = a[lane * 2], a1 = a[lane * 2 + 1];
    float4 b0 = b[lane * 2], b1 = b[lane * 2 + 1];

    float ssi = a0.x*a0.x + a0.y*a0.y + a0.z*a0.z + a0.w*a0.w
              + a1.x*a1.x + a1.y*a1.y + a1.z*a1.z + a1.w*a1.w;
    float ssj = b0.x*b0.x + b0.y*b0.y + b0.z*b0.z + b0.w*b0.w
              + b1.x*b1.x + b1.y*b1.y + b1.z*b1.z + b1.w*b1.w;
    float dp  = a0.x*b0.x + a0.y*b0.y + a0.z*b0.z + a0.w*b0.w
              + a1.x*b1.x + a1.y*b1.y + a1.z*b1.z + a1.w*b1.w;
    #pragma unroll
    for (int off = 32; off; off >>= 1) {
        ssi += __shfl_xor(ssi, off, 64);
        ssj += __shfl_xor(ssj, off, 64);
        dp  += __shfl_xor(dp,  off, 64);
    }
    const float invi = rsqrtf(ssi), invj = rsqrtf(ssj);

    const float zi[8] = {a0.x*invi, a0.y*invi, a0.z*invi, a0.w*invi,
                         a1.x*invi, a1.y*invi, a1.z*invi, a1.w*invi};
    const float zj[8] = {b0.x*invj, b0.y*invj, b0.z*invj, b0.w*invj,
                         b1.x*invj, b1.y*invj, b1.z*invj, b1.w*invj};

    int pi0 = __builtin_amdgcn_cvt_pk_fp8_f32(zi[0], zi[1], 0, false);
    pi0     = __builtin_amdgcn_cvt_pk_fp8_f32(zi[2], zi[3], pi0, true);
    int pi1 = __builtin_amdgcn_cvt_pk_fp8_f32(zi[4], zi[5], 0, false);
    pi1     = __builtin_amdgcn_cvt_pk_fp8_f32(zi[6], zi[7], pi1, true);
    int pj0 = __builtin_amdgcn_cvt_pk_fp8_f32(zj[0], zj[1], 0, false);
    pj0     = __builtin_amdgcn_cvt_pk_fp8_f32(zj[2], zj[3], pj0, true);
    int pj1 = __builtin_amdgcn_cvt_pk_fp8_f32(zj[4], zj[5], 0, false);
    pj1     = __builtin_amdgcn_cvt_pk_fp8_f32(zj[6], zj[7], pj1, true);

    float dssi = 0.f, dssj = 0.f;
    SS_FP8(pi0, dssi);
    SS_FP8(pi1, dssi);
    SS_FP8(pj0, dssj);
    SS_FP8(pj1, dssj);

    // blocked-tile store (see layout comment above)
    const size_t off8 = (size_t)((k >> 5) * 8 + (lane >> 3)) * 2048
                      + (size_t)(((lane >> 1) & 1)) * 1024
                      + (size_t)(((k & 31) * 2 + ((lane >> 2) & 1))) * 16
                      + (size_t)((lane & 1)) * 8;
    const unsigned long long vi =
        ((unsigned long long)(unsigned)pi1 << 32) | (unsigned)pi0;
    const unsigned long long vj =
        ((unsigned long long)(unsigned)pj1 << 32) | (unsigned)pj0;
    *(unsigned long long*)(zb + off8)                       = vi;
    *(unsigned long long*)(zb + off8 + (size_t)N_ROWS * D)  = vj;

    #pragma unroll
    for (int off = 32; off; off >>= 1) {
        dssi += __shfl_xor(dssi, off, 64);
        dssj += __shfl_xor(dssj, off, 64);
    }
    if (lane == 0) {
        diagss[k]          = dssi;
        diagss[k + N_ROWS] = dssj;
        pos[k]             = 2.0f * dp * invi * invj;
    }
}

// ---------------------------------------------------------------------------
// Kernel 2: symmetric fused sim-GEMM, MX fp8 (e4m3, unit scales), NO LDS
// STAGING. zb (4 MB) is L2-resident; fragments load directly global->VGPR
// (guide Common-mistake #7: staging L2-fit data is pure overhead -- and the
// R2-R6 ledger shows every LDS-staging schedule was latency-bound on the
// global_load_lds path: time ~ latency/concurrency, all pipes <25% busy).
//
// 128x128 tile, 4 waves 2x2 (wave owns 64x64 = 2x2 32x32 frags), 2080
// upper-tri blocks. Per K-iter per wave: 8 dense 1KB global_load_dwordx4
// (4 fragments x 2 planes), software-pipelined 1 iter deep (static [it&1]
// indexing after full unroll); 4 MFMA. No barriers in the K-loop; compiler
// inserts fine-grained vmcnt waits. Epilogue (verified R2/R3/R5): C/D map
// col=l31, row=(reg&3)+8*(reg>>2)+4*half; rp/cp LDS reduce; row/col mirror.
// ---------------------------------------------------------------------------
__global__ __launch_bounds__(256, 3) void simgemm_kernel(
    const uint8_t* __restrict__ zb, float* __restrict__ partials)
{
    __shared__ float rp[4][64];    // per-wave row partials
    __shared__ float cp4[4][64];   // per-wave col partials

    const int tid  = threadIdx.x;
    const int wave = tid >> 6, lane = tid & 63;
    const int l31  = lane & 31, half = lane >> 5;

    // Decode linear block id -> (bi, bj), bi <= bj. cum(bi) = bi*(129-bi)/2.
    const int t = blockIdx.x;
    int bi = (int)((129.0f - sqrtf(129.0f * 129.0f - 8.0f * (float)t)) * 0.5f);
    while (bi > 0 && bi * (129 - bi) / 2 > t) --bi;
    while ((bi + 1) * (129 - (bi + 1)) / 2 <= t) ++bi;
    const int bj = bi + (t - bi * (129 - bi) / 2);
    const bool diag = (bi == bj);

    const int wr = wave >> 1, wc = wave & 1;

    // Fragment base pointers. Row-block of A-frag f: R = bi*4 + wr*2 + f
    // (tile rows bi*128 + wr*64 + f*32). Per-lane dense offset (2*l31+half)*16.
    const int lofs = ((l31 << 1) | half) * 16;
    const uint8_t* baseA0 = zb + (size_t)(bi * 4 + wr * 2    ) * 8 * 2048 + lofs;
    const uint8_t* baseA1 = zb + (size_t)(bi * 4 + wr * 2 + 1) * 8 * 2048 + lofs;
    const uint8_t* baseB0 = zb + (size_t)(bj * 4 + wc * 2    ) * 8 * 2048 + lofs;
    const uint8_t* baseB1 = zb + (size_t)(bj * 4 + wc * 2 + 1) * 8 * 2048 + lofs;

    // load fragment for k-iter IT from tile base BP: two dense 1KB dwordx4
#define LDFRAG(DST, BP, IT)                                                         \
    do {                                                                            \
        i32x4 _lo = *(const i32x4*)((BP) + (size_t)(IT) * 2048);                    \
        i32x4 _hi = *(const i32x4*)((BP) + (size_t)(IT) * 2048 + 1024);             \
        DST = __builtin_shufflevector(_lo, _hi, 0, 1, 2, 3, 4, 5, 6, 7);            \
    } while (0)

    f32x16 acc[2][2] = {};
    i32x8 fA0[2], fA1[2], fB0[2], fB1[2];

    LDFRAG(fA0[0], baseA0, 0);
    LDFRAG(fA1[0], baseA1, 0);
    LDFRAG(fB0[0], baseB0, 0);
    LDFRAG(fB1[0], baseB1, 0);

    #pragma unroll
    for (int it = 0; it < NKT; ++it) {
        const int cur = it & 1, nxt = cur ^ 1;
        if (it + 1 < NKT) {   // prefetch next K-chunk while MFMAing current
            LDFRAG(fA0[nxt], baseA0, it + 1);
            LDFRAG(fA1[nxt], baseA1, it + 1);
            LDFRAG(fB0[nxt], baseB0, it + 1);
            LDFRAG(fB1[nxt], baseB1, it + 1);
        }
        acc[0][0] = __builtin_amdgcn_mfma_scale_f32_32x32x64_f8f6f4(
            fA0[cur], fB0[cur], acc[0][0], 0, 0, 0, 0x7f7f7f7f, 0, 0x7f7f7f7f);
        acc[0][1] = __builtin_amdgcn_mfma_scale_f32_32x32x64_f8f6f4(
            fA0[cur], fB1[cur], acc[0][1], 0, 0, 0, 0x7f7f7f7f, 0, 0x7f7f7f7f);
        acc[1][0] = __builtin_amdgcn_mfma_scale_f32_32x32x64_f8f6f4(
            fA1[cur], fB0[cur], acc[1][0], 0, 0, 0, 0x7f7f7f7f, 0, 0x7f7f7f7f);
        acc[1][1] = __builtin_amdgcn_mfma_scale_f32_32x32x64_f8f6f4(
            fA1[cur], fB1[cur], acc[1][1], 0, 0, 0, 0x7f7f7f7f, 0, 0x7f7f7f7f);
    }

    // Epilogue. C/D 32x32 layout: col = l31, row = (reg&3)+8*(reg>>2)+4*half
    // within each 32x32 frag. e = exp(sim/T) = exp(2*acc).
    float rowp[2][16] = {};
    #pragma unroll
    for (int j = 0; j < 2; ++j) {
        float cpj = 0.f;
        #pragma unroll
        for (int i = 0; i < 2; ++i)
            #pragma unroll
            for (int r = 0; r < 16; ++r) {
                float e = __expf(2.0f * acc[i][j][r]);
                rowp[i][r] += e;
                cpj += e;
            }
        if (!diag) {   // col partial over this wave's 64 rows
            cpj += __shfl_xor(cpj, 32, 64);
            if (half == 0) cp4[wave][j * 32 + l31] = cpj;
        }
    }
    #pragma unroll
    for (int i = 0; i < 2; ++i)
        #pragma unroll
        for (int r = 0; r < 16; ++r) {
            float e = rowp[i][r];
            e += __shfl_xor(e, 1, 64);
            e += __shfl_xor(e, 2, 64);
            e += __shfl_xor(e, 4, 64);
            e += __shfl_xor(e, 8, 64);
            e += __shfl_xor(e, 16, 64);
            if (l31 == 0)
                rp[wave][i * 32 + (r & 3) + 8 * (r >> 2) + 4 * half] = e;
        }
    __syncthreads();

    // rows 0-63 from waves {0,1}, 64-127 from {2,3};
    // cols 0-63 from waves {0,2}, 64-127 from {1,3}.
    float* pA = partials + (size_t)(bi * NTILE + bj) * 128;
    float* pB = partials + (size_t)(bj * NTILE + bi) * 128;
    if (tid < 128) {
        const int h = tid >> 6, rr = tid & 63;
        pA[tid] = rp[h * 2][rr] + rp[h * 2 + 1][rr];
    } else if (!diag) {
        const int c = tid - 128, h = c >> 6, cc = c & 63;
        pB[c] = cp4[h][cc] + cp4[h + 2][cc];
    }
}

// ---------------------------------------------------------------------------
// Kernel 3: per-tile-row reduction of partials + log terms + pos chunk.
// ---------------------------------------------------------------------------
__global__ __launch_bounds__(256) void rowfin_kernel(
    const float* __restrict__ partials, const float* __restrict__ diagss,
    const float* __restrict__ pos, float* __restrict__ lgpart)
{
    const int r  = blockIdx.x;          // tile-row 0..63
    const int ri = threadIdx.x & 127;   // row within tile
    const int ch = threadIdx.x >> 7;    // c-half 0/1
    const float* base = partials + (size_t)r * NTILE * 128 + ri;
    float s = 0.f;
    #pragma unroll
    for (int c = 0; c < 32; ++c)
        s += base[(size_t)(ch * 32 + c) * 128];
    __shared__ float half1[128];
    __shared__ float red[4];
    if (ch == 1) half1[ri] = s;
    __syncthreads();
    float lg = 0.f;
    if (ch == 0) {
        float rs = s + half1[ri];
        int row = r * 128 + ri;
        lg = __logf(rs - __expf(2.0f * diagss[row]));
    }
    if (threadIdx.x < 64)
        lg -= 2.0f * pos[r * 64 + threadIdx.x];
    #pragma unroll
    for (int off = 32; off; off >>= 1) lg += __shfl_xor(lg, off, 64);
    const int wave = threadIdx.x >> 6, lane = threadIdx.x & 63;
    if (lane == 0) red[wave] = lg;
    __syncthreads();
    if (threadIdx.x == 0) lgpart[r] = red[0] + red[1] + red[2] + red[3];
}

// ---------------------------------------------------------------------------
// Kernel 4: loss = sum_r lgpart[r] / 8192   (one wave)
// ---------------------------------------------------------------------------
__global__ __launch_bounds__(64) void loss_kernel(
    const float* __restrict__ lgpart, float* __restrict__ out)
{
    float local = lgpart[threadIdx.x];
    #pragma unroll
    for (int off = 32; off; off >>= 1) local += __shfl_xor(local, off, 64);
    if (threadIdx.x == 0) out[0] = local * (1.0f / 8192.0f);
}

// ---------------------------------------------------------------------------
extern "C" void kernel_launch(void* const* d_in, const int* in_sizes, int n_in,
                              void* d_out, int out_size, void* d_ws, size_t ws_size,
                              hipStream_t stream)
{
    const float* emb_i = (const float*)d_in[0];
    const float* emb_j = (const float*)d_in[1];

    // ws layout: zb fp8 [M][D] (4 MB, blocked-tile) | partials f32[64][64][128]
    //            (2 MB) | diagss f32[M] | pos f32[N] | lgpart f32[64]
    uint8_t* zb = (uint8_t*)d_ws;
    float* partials = (float*)((char*)d_ws + (size_t)M * D);
    float* diagss   = partials + (size_t)NTILE * NTILE * 128;
    float* pos      = diagss + M;
    float* lgpart   = pos + N_ROWS;
    float* out      = (float*)d_out;

    normpos_kernel<<<N_ROWS / 4, 256, 0, stream>>>(emb_i, emb_j, zb, diagss, pos);
    simgemm_kernel<<<NBLK, 256, 0, stream>>>(zb, partials);
    rowfin_kernel<<<NTILE, 256, 0, stream>>>(partials, diagss, pos, lgpart);
    loss_kernel<<<1, 64, 0, stream>>>(lgpart, out);
}

// Round 8
// 104.644 us; speedup vs baseline: 1.2767x; 1.0367x over previous
//
#include <hip/hip_runtime.h>
#include <cstdint>
#include <cstddef>

// Problem constants (fixed by the reference: N=4096, D=512)
constexpr int N_ROWS = 4096;
constexpr int D      = 512;
constexpr int M      = 8192;   // 2N
constexpr int NTILE  = 64;     // M / 128 : partials chunk grid
constexpr int NBLK   = NTILE * (NTILE + 1) / 2;   // 2080 upper-tri tile pairs
constexpr int NKT    = 8;      // K-iterations (64 k-bytes each)

using f32x16 = __attribute__((ext_vector_type(16))) float;
using i32x4  = __attribute__((ext_vector_type(4))) int;
using i32x8  = __attribute__((ext_vector_type(8))) int;

// sum of squares of the 4 fp8 e4m3 bytes in `pk` (selector must be literal)
#define SS_FP8(pk, accum)                                                           \
    do {                                                                            \
        float f0 = __builtin_amdgcn_cvt_f32_fp8((pk), 0);                           \
        float f1 = __builtin_amdgcn_cvt_f32_fp8((pk), 1);                           \
        float f2 = __builtin_amdgcn_cvt_f32_fp8((pk), 2);                           \
        float f3 = __builtin_amdgcn_cvt_f32_fp8((pk), 3);                           \
        (accum) += f0 * f0 + f1 * f1 + f2 * f2 + f3 * f3;                           \
    } while (0)

// ---------------------------------------------------------------------------
// zb BLOCKED-TILE layout (fp8 e4m3) for direct global->VGPR fragment loads
// with perfect coalescing (VERIFIED R7, absmax 0.0):
//   tile(R, C) = rows [R*32, R*32+32) x k-bytes [C*64, C*64+64), 2048 B,
//   at offset (R*8 + C)*2048.  In-tile: off = (g&1)*1024 + (r*2+(g>>1))*16+b.
//   MFMA lane (l31, half): two dense-1KB loads at (2*l31+half)*16 (+0,+1024)
//   -> 32 contiguous k-bytes/lane == the verified MX fragment.
// ---------------------------------------------------------------------------

// ---------------------------------------------------------------------------
// Kernel 1: fused normalize + fp8-quantize + positive-pair logits (VERIFIED).
// ---------------------------------------------------------------------------
__global__ __launch_bounds__(256) void normpos_kernel(
    const float* __restrict__ emb_i, const float* __restrict__ emb_j,
    uint8_t* __restrict__ zb, float* __restrict__ diagss,
    float* __restrict__ pos)
{
    const int wave = threadIdx.x >> 6, lane = threadIdx.x & 63;
    const int k = blockIdx.x * 4 + wave;

    const float4* a = (const float4*)(emb_i + (size_t)k * D);
    const float4* b = (const float4*)(emb_j + (size_t)k * D);
    float4 a0 = a[lane * 2], a1 = a[lane * 2 + 1];
    float4 b0 = b[lane * 2], b1 = b[lane * 2 + 1];

    float ssi = a0.x*a0.x + a0.y*a0.y + a0.z*a0.z + a0.w*a0.w
              + a1.x*a1.x + a1.y*a1.y + a1.z*a1.z + a1.w*a1.w;
    float ssj = b0.x*b0.x + b0.y*b0.y + b0.z*b0.z + b0.w*b0.w
              + b1.x*b1.x + b1.y*b1.y + b1.z*b1.z + b1.w*b1.w;
    float dp  = a0.x*b0.x + a0.y*b0.y + a0.z*b0.z + a0.w*b0.w
              + a1.x*b1.x + a1.y*b1.y + a1.z*b1.z + a1.w*b1.w;
    #pragma unroll
    for (int off = 32; off; off >>= 1) {
        ssi += __shfl_xor(ssi, off, 64);
        ssj += __shfl_xor(ssj, off, 64);
        dp  += __shfl_xor(dp,  off, 64);
    }
    const float invi = rsqrtf(ssi), invj = rsqrtf(ssj);

    const float zi[8] = {a0.x*invi, a0.y*invi, a0.z*invi, a0.w*invi,
                         a1.x*invi, a1.y*invi, a1.z*invi, a1.w*invi};
    const float zj[8] = {b0.x*invj, b0.y*invj, b0.z*invj, b0.w*invj,
                         b1.x*invj, b1.y*invj, b1.z*invj, b1.w*invj};

    int pi0 = __builtin_amdgcn_cvt_pk_fp8_f32(zi[0], zi[1], 0, false);
    pi0     = __builtin_amdgcn_cvt_pk_fp8_f32(zi[2], zi[3], pi0, true);
    int pi1 = __builtin_amdgcn_cvt_pk_fp8_f32(zi[4], zi[5], 0, false);
    pi1     = __builtin_amdgcn_cvt_pk_fp8_f32(zi[6], zi[7], pi1, true);
    int pj0 = __builtin_amdgcn_cvt_pk_fp8_f32(zj[0], zj[1], 0, false);
    pj0     = __builtin_amdgcn_cvt_pk_fp8_f32(zj[2], zj[3], pj0, true);
    int pj1 = __builtin_amdgcn_cvt_pk_fp8_f32(zj[4], zj[5], 0, false);
    pj1     = __builtin_amdgcn_cvt_pk_fp8_f32(zj[6], zj[7], pj1, true);

    float dssi = 0.f, dssj = 0.f;
    SS_FP8(pi0, dssi);
    SS_FP8(pi1, dssi);
    SS_FP8(pj0, dssj);
    SS_FP8(pj1, dssj);

    // blocked-tile store (see layout comment above)
    const size_t off8 = (size_t)((k >> 5) * 8 + (lane >> 3)) * 2048
                      + (size_t)(((lane >> 1) & 1)) * 1024
                      + (size_t)(((k & 31) * 2 + ((lane >> 2) & 1))) * 16
                      + (size_t)((lane & 1)) * 8;
    const unsigned long long vi =
        ((unsigned long long)(unsigned)pi1 << 32) | (unsigned)pi0;
    const unsigned long long vj =
        ((unsigned long long)(unsigned)pj1 << 32) | (unsigned)pj0;
    *(unsigned long long*)(zb + off8)                       = vi;
    *(unsigned long long*)(zb + off8 + (size_t)N_ROWS * D)  = vj;

    #pragma unroll
    for (int off = 32; off; off >>= 1) {
        dssi += __shfl_xor(dssi, off, 64);
        dssj += __shfl_xor(dssj, off, 64);
    }
    if (lane == 0) {
        diagss[k]          = dssi;
        diagss[k + N_ROWS] = dssj;
        pos[k]             = 2.0f * dp * invi * invj;
    }
}

// ---------------------------------------------------------------------------
// Kernel 2: symmetric fused sim-GEMM, MX fp8 (e4m3, unit scales), no LDS
// staging (VERIFIED R7 structure). R8 deltas, each counter-verifiable:
//  1. Bijective XCD swizzle (2080 = 8 x 260): logical tile
//     t = (bid&7)*260 + (bid>>3) -> consecutive upper-tri tiles (shared
//     A-panel, adjacent B-panels) co-locate on one XCD's L2. R7 served
//     ~532 MB at ~11.8 TB/s (L3-like); L2-local service is ~3x.
//  2. REAL 1-deep pipeline: R7's VGPR_Count=68 proves the compiler sank the
//     prefetch next to its use (zero latency hiding). Explicit two named
//     fragment sets (rule #20), unroll-by-2, sched_barrier(0) pinning the
//     next-iter loads ABOVE the MFMA cluster -> compiler emits counted
//     vmcnt(8), loads fly across the whole MFMA+epilogue of the iteration.
//  3. launch_bounds(256,2): budget for the double-buffer (~130-160 VGPR).
// ---------------------------------------------------------------------------
__global__ __launch_bounds__(256, 2) void simgemm_kernel(
    const uint8_t* __restrict__ zb, float* __restrict__ partials)
{
    __shared__ float rp[4][64];    // per-wave row partials
    __shared__ float cp4[4][64];   // per-wave col partials

    const int tid  = threadIdx.x;
    const int wave = tid >> 6, lane = tid & 63;
    const int l31  = lane & 31, half = lane >> 5;

    // XCD-bijective swizzle, then decode t -> (bi, bj), bi <= bj.
    const int t = ((int)(blockIdx.x & 7)) * (NBLK / 8) + ((int)blockIdx.x >> 3);
    int bi = (int)((129.0f - sqrtf(129.0f * 129.0f - 8.0f * (float)t)) * 0.5f);
    while (bi > 0 && bi * (129 - bi) / 2 > t) --bi;
    while ((bi + 1) * (129 - (bi + 1)) / 2 <= t) ++bi;
    const int bj = bi + (t - bi * (129 - bi) / 2);
    const bool diag = (bi == bj);

    const int wr = wave >> 1, wc = wave & 1;

    // Fragment base pointers (blocked-tile layout).
    const int lofs = ((l31 << 1) | half) * 16;
    const uint8_t* baseA0 = zb + (size_t)(bi * 4 + wr * 2    ) * 8 * 2048 + lofs;
    const uint8_t* baseA1 = zb + (size_t)(bi * 4 + wr * 2 + 1) * 8 * 2048 + lofs;
    const uint8_t* baseB0 = zb + (size_t)(bj * 4 + wc * 2    ) * 8 * 2048 + lofs;
    const uint8_t* baseB1 = zb + (size_t)(bj * 4 + wc * 2 + 1) * 8 * 2048 + lofs;

#define LDFRAG(DST, BP, IT)                                                         \
    do {                                                                            \
        i32x4 _lo = *(const i32x4*)((BP) + (size_t)(IT) * 2048);                    \
        i32x4 _hi = *(const i32x4*)((BP) + (size_t)(IT) * 2048 + 1024);             \
        DST = __builtin_shufflevector(_lo, _hi, 0, 1, 2, 3, 4, 5, 6, 7);            \
    } while (0)

#define MFMA4(A0, A1, B0, B1)                                                       \
    do {                                                                            \
        acc[0][0] = __builtin_amdgcn_mfma_scale_f32_32x32x64_f8f6f4(                \
            A0, B0, acc[0][0], 0, 0, 0, 0x7f7f7f7f, 0, 0x7f7f7f7f);                 \
        acc[0][1] = __builtin_amdgcn_mfma_scale_f32_32x32x64_f8f6f4(                \
            A0, B1, acc[0][1], 0, 0, 0, 0x7f7f7f7f, 0, 0x7f7f7f7f);                 \
        acc[1][0] = __builtin_amdgcn_mfma_scale_f32_32x32x64_f8f6f4(                \
            A1, B0, acc[1][0], 0, 0, 0, 0x7f7f7f7f, 0, 0x7f7f7f7f);                 \
        acc[1][1] = __builtin_amdgcn_mfma_scale_f32_32x32x64_f8f6f4(                \
            A1, B1, acc[1][1], 0, 0, 0, 0x7f7f7f7f, 0, 0x7f7f7f7f);                 \
    } while (0)

    f32x16 acc[2][2] = {};
    // Two named fragment sets (static indexing only -- rule #20).
    i32x8 cA0, cA1, cB0, cB1;   // "current"
    i32x8 nA0, nA1, nB0, nB1;   // "next"

    LDFRAG(cA0, baseA0, 0);
    LDFRAG(cA1, baseA1, 0);
    LDFRAG(cB0, baseB0, 0);
    LDFRAG(cB1, baseB1, 0);

    #pragma unroll
    for (int it = 0; it < NKT; it += 2) {
        // even sub-iter: compute c-set, prefetch (it+1) into n-set
        if (it + 1 < NKT) {
            LDFRAG(nA0, baseA0, it + 1);
            LDFRAG(nA1, baseA1, it + 1);
            LDFRAG(nB0, baseB0, it + 1);
            LDFRAG(nB1, baseB1, it + 1);
        }
        __builtin_amdgcn_sched_barrier(0);   // loads stay ABOVE the MFMAs
        MFMA4(cA0, cA1, cB0, cB1);

        // odd sub-iter: compute n-set, prefetch (it+2) into c-set
        if (it + 2 < NKT) {
            LDFRAG(cA0, baseA0, it + 2);
            LDFRAG(cA1, baseA1, it + 2);
            LDFRAG(cB0, baseB0, it + 2);
            LDFRAG(cB1, baseB1, it + 2);
        }
        __builtin_amdgcn_sched_barrier(0);
        MFMA4(nA0, nA1, nB0, nB1);
    }

    // Epilogue (VERIFIED). C/D 32x32: col=l31, row=(reg&3)+8*(reg>>2)+4*half.
    // e = exp(sim/T) = exp(2*acc).
    float rowp[2][16] = {};
    #pragma unroll
    for (int j = 0; j < 2; ++j) {
        float cpj = 0.f;
        #pragma unroll
        for (int i = 0; i < 2; ++i)
            #pragma unroll
            for (int r = 0; r < 16; ++r) {
                float e = __expf(2.0f * acc[i][j][r]);
                rowp[i][r] += e;
                cpj += e;
            }
        if (!diag) {   // col partial over this wave's 64 rows
            cpj += __shfl_xor(cpj, 32, 64);
            if (half == 0) cp4[wave][j * 32 + l31] = cpj;
        }
    }
    #pragma unroll
    for (int i = 0; i < 2; ++i)
        #pragma unroll
        for (int r = 0; r < 16; ++r) {
            float e = rowp[i][r];
            e += __shfl_xor(e, 1, 64);
            e += __shfl_xor(e, 2, 64);
            e += __shfl_xor(e, 4, 64);
            e += __shfl_xor(e, 8, 64);
            e += __shfl_xor(e, 16, 64);
            if (l31 == 0)
                rp[wave][i * 32 + (r & 3) + 8 * (r >> 2) + 4 * half] = e;
        }
    __syncthreads();

    // rows 0-63 from waves {0,1}, 64-127 from {2,3};
    // cols 0-63 from waves {0,2}, 64-127 from {1,3}.
    float* pA = partials + (size_t)(bi * NTILE + bj) * 128;
    float* pB = partials + (size_t)(bj * NTILE + bi) * 128;
    if (tid < 128) {
        const int h = tid >> 6, rr = tid & 63;
        pA[tid] = rp[h * 2][rr] + rp[h * 2 + 1][rr];
    } else if (!diag) {
        const int c = tid - 128, h = c >> 6, cc = c & 63;
        pB[c] = cp4[h][cc] + cp4[h + 2][cc];
    }
}

// ---------------------------------------------------------------------------
// Kernel 3: per-tile-row reduction of partials + log terms + pos chunk.
// ---------------------------------------------------------------------------
__global__ __launch_bounds__(256) void rowfin_kernel(
    const float* __restrict__ partials, const float* __restrict__ diagss,
    const float* __restrict__ pos, float* __restrict__ lgpart)
{
    const int r  = blockIdx.x;          // tile-row 0..63
    const int ri = threadIdx.x & 127;   // row within tile
    const int ch = threadIdx.x >> 7;    // c-half 0/1
    const float* base = partials + (size_t)r * NTILE * 128 + ri;
    float s = 0.f;
    #pragma unroll
    for (int c = 0; c < 32; ++c)
        s += base[(size_t)(ch * 32 + c) * 128];
    __shared__ float half1[128];
    __shared__ float red[4];
    if (ch == 1) half1[ri] = s;
    __syncthreads();
    float lg = 0.f;
    if (ch == 0) {
        float rs = s + half1[ri];
        int row = r * 128 + ri;
        lg = __logf(rs - __expf(2.0f * diagss[row]));
    }
    if (threadIdx.x < 64)
        lg -= 2.0f * pos[r * 64 + threadIdx.x];
    #pragma unroll
    for (int off = 32; off; off >>= 1) lg += __shfl_xor(lg, off, 64);
    const int wave = threadIdx.x >> 6, lane = threadIdx.x & 63;
    if (lane == 0) red[wave] = lg;
    __syncthreads();
    if (threadIdx.x == 0) lgpart[r] = red[0] + red[1] + red[2] + red[3];
}

// ---------------------------------------------------------------------------
// Kernel 4: loss = sum_r lgpart[r] / 8192   (one wave)
// ---------------------------------------------------------------------------
__global__ __launch_bounds__(64) void loss_kernel(
    const float* __restrict__ lgpart, float* __restrict__ out)
{
    float local = lgpart[threadIdx.x];
    #pragma unroll
    for (int off = 32; off; off >>= 1) local += __shfl_xor(local, off, 64);
    if (threadIdx.x == 0) out[0] = local * (1.0f / 8192.0f);
}

// ---------------------------------------------------------------------------
extern "C" void kernel_launch(void* const* d_in, const int* in_sizes, int n_in,
                              void* d_out, int out_size, void* d_ws, size_t ws_size,
                              hipStream_t stream)
{
    const float* emb_i = (const float*)d_in[0];
    const float* emb_j = (const float*)d_in[1];

    // ws layout: zb fp8 [M][D] (4 MB, blocked-tile) | partials f32[64][64][128]
    //            (2 MB) | diagss f32[M] | pos f32[N] | lgpart f32[64]
    uint8_t* zb = (uint8_t*)d_ws;
    float* partials = (float*)((char*)d_ws + (size_t)M * D);
    float* diagss   = partials + (size_t)NTILE * NTILE * 128;
    float* pos      = diagss + M;
    float* lgpart   = pos + N_ROWS;
    float* out      = (float*)d_out;

    normpos_kernel<<<N_ROWS / 4, 256, 0, stream>>>(emb_i, emb_j, zb, diagss, pos);
    simgemm_kernel<<<NBLK, 256, 0, stream>>>(zb, partials);
    rowfin_kernel<<<NTILE, 256, 0, stream>>>(partials, diagss, pos, lgpart);
    loss_kernel<<<1, 64, 0, stream>>>(lgpart, out);
}